// Round 7
// baseline (212.859 us; speedup 1.0000x reference)
//
#include <hip/hip_runtime.h>
#include <stdint.h>

// B=16, CIN=512, COUT=128, H=W=64
#define NB    16
#define CIN   512
#define COUT  128
#define HW    4096
#define BN    64              // N-tile per block
#define BK    32              // K-tile per iteration
#define NIT   (CIN / BK)      // 16
// grid = 16 b x 64 n-tiles = 1024 blocks x 512 thr = 4 blocks/CU = 32 waves/CU

using bf16x8  = __attribute__((ext_vector_type(8))) __bf16;
using floatx4 = __attribute__((ext_vector_type(4))) float;

// RNE float -> bf16 bits (proven R1-R6)
__device__ __forceinline__ unsigned short f2bf_bits(float f) {
    union { float f; unsigned u; } v; v.f = f;
    return (unsigned short)((v.u + 0x7fffu + ((v.u >> 16) & 1u)) >> 16);
}

// async global->LDS, 16B/lane; LDS dest = wave-uniform base + lane*16
#define GLD16(g, l)                                                            \
    __builtin_amdgcn_global_load_lds(                                          \
        (const __attribute__((address_space(1))) void*)(g),                    \
        (__attribute__((address_space(3))) void*)(l), 16, 0, 0)

// ---------------------------------------------------------------------------
// Precompute mw[b][k8][m][j] = bf16(weight[m][k8*8+j] * style[b][k8*8+j])
// = the 16x16x32 A-fragment layout, contiguous 8KB slab per K-tile.
// ---------------------------------------------------------------------------
__global__ __launch_bounds__(256)
void modw_kernel(const float* __restrict__ style,
                 const float* __restrict__ weight,
                 __bf16* __restrict__ mw)
{
    const int id = blockIdx.x * 256 + threadIdx.x;   // 512 blocks
    const int k8 = id & 63;
    const int m  = (id >> 6) & 127;
    const int b  = id >> 13;

    const float4 w0 = *(const float4*)(weight + m * CIN + k8 * 8);
    const float4 w1 = *(const float4*)(weight + m * CIN + k8 * 8 + 4);
    const float4 s0 = *(const float4*)(style + b * CIN + k8 * 8);
    const float4 s1 = *(const float4*)(style + b * CIN + k8 * 8 + 4);

    union { unsigned short us[8]; bf16x8 v; } pk;
    pk.us[0] = f2bf_bits(w0.x * s0.x);
    pk.us[1] = f2bf_bits(w0.y * s0.y);
    pk.us[2] = f2bf_bits(w0.z * s0.z);
    pk.us[3] = f2bf_bits(w0.w * s0.w);
    pk.us[4] = f2bf_bits(w1.x * s1.x);
    pk.us[5] = f2bf_bits(w1.y * s1.y);
    pk.us[6] = f2bf_bits(w1.z * s1.z);
    pk.us[7] = f2bf_bits(w1.w * s1.w);
    *(bf16x8*)(mw + ((size_t)(b * 64 + k8) * 128 + m) * 8) = pk.v;
}

// ---------------------------------------------------------------------------
// 32-waves/CU variant: 512 thr/block, wave tile 64(m) x 16(n), VGPR<=64.
//  A: dbuf LDS via global_load_lds (1 KB/wave/step, zero regs).
//  B: direct global->reg (8 x 4B coalesced 64B segments), convert in regs.
// ---------------------------------------------------------------------------
__global__ __launch_bounds__(512, 8)
void modconv1x1_kernel(const float* __restrict__ x,
                       const __bf16* __restrict__ mw,
                       float* __restrict__ out)
{
    __shared__ __align__(16) __bf16 Alds[2][4096];   // [k8][m][j], 2 x 8 KB

    const int tid  = threadIdx.x;
    const int lane = tid & 63;
    const int wave = tid >> 6;          // 0..7
    const int quad = lane >> 4;
    const int l15  = lane & 15;

    const int b  = blockIdx.x >> 6;
    const int n0 = (blockIdx.x & 63) * BN;

    const int wm = (wave & 1) * 64;     // wave tile 64(m) x 16(n)
    const int wn = (wave >> 1) * 16;

    const float* xbw  = x   + (size_t)b * CIN * HW + n0 + wn;   // + l15 per lane
    float*       outb = out + (size_t)b * COUT * HW + n0;
    const char*  mwb  = (const char*)mw + (size_t)b * (64 * 128 * 16);  // 128KB/batch

    floatx4 acc[4];
    #pragma unroll
    for (int i = 0; i < 4; ++i) acc[i] = (floatx4){0.f, 0.f, 0.f, 0.f};

    // prologue: A tile 0 -> buf 0 (1 GLD16 per wave)
    {
        char* al = (char*)&Alds[0][0];
        GLD16(mwb + wave * 1024 + lane * 16, al + wave * 1024);
    }

    int cur = 0;
    for (int it = 0; it < NIT; ++it) {
        const int k0 = it * BK;
        __syncthreads();   // A buf[cur] complete; prior reads of buf[cur^1] done

        if (it + 1 < NIT) {
            const char* at = mwb + (size_t)(it + 1) * BK * 256;
            char*       al = (char*)&Alds[cur ^ 1][0];
            GLD16(at + wave * 1024 + lane * 16, al + wave * 1024);
        }

        // B: 8 direct loads (lane quad,l15 -> rows k0+quad*8+j, col wn+l15)
        float rbf[8];
        {
            const float* src = xbw + (size_t)(k0 + quad * 8) * HW + l15;
            #pragma unroll
            for (int j = 0; j < 8; ++j)
                rbf[j] = src[(size_t)j * HW];
        }

        // A fragments: 4x ds_read_b128 from buf[cur]
        bf16x8 af[4];
        #pragma unroll
        for (int tm = 0; tm < 4; ++tm)
            af[tm] = *(const bf16x8*)&Alds[cur][(quad * COUT + wm + tm * 16 + l15) * 8];

        // convert B -> fragment
        union { unsigned short us[8]; bf16x8 v; } pk;
        #pragma unroll
        for (int j = 0; j < 8; ++j) pk.us[j] = f2bf_bits(rbf[j]);

        #pragma unroll
        for (int tm = 0; tm < 4; ++tm)
            acc[tm] = __builtin_amdgcn_mfma_f32_16x16x32_bf16(
                af[tm], pk.v, acc[tm], 0, 0, 0);

        cur ^= 1;
    }

    // epilogue: C/D layout col(n)=l15, row(o)=quad*4+reg
    #pragma unroll
    for (int tm = 0; tm < 4; ++tm) {
        const int o = wm + tm * 16 + quad * 4;
        const int n = wn + l15;
        #pragma unroll
        for (int r = 0; r < 4; ++r)
            outb[(size_t)(o + r) * HW + n] = acc[tm][r];
    }
}

extern "C" void kernel_launch(void* const* d_in, const int* in_sizes, int n_in,
                              void* d_out, int out_size, void* d_ws, size_t ws_size,
                              hipStream_t stream) {
    const float* x      = (const float*)d_in[0];   // (16, 512, 64, 64) fp32
    const float* style  = (const float*)d_in[1];   // (16, 512) fp32
    const float* weight = (const float*)d_in[2];   // (128, 512) fp32
    float* out = (float*)d_out;                    // (16, 128, 64, 64) fp32
    __bf16* mw = (__bf16*)d_ws;                    // 2 MB modulated weights

    modw_kernel<<<dim3(512), dim3(256), 0, stream>>>(style, weight, mw);
    modconv1x1_kernel<<<dim3(NB * BN), dim3(512), 0, stream>>>(x, mw, out);
}